// Round 1
// 197.599 us; speedup vs baseline: 1.0587x; 1.0587x over previous
//
#include <hip/hip_runtime.h>

// Factored single-row attention (reference returns out[:, -1, :] only).
// ws layout (floats): M2p [0,65536) packed [k4][e][4]; Wvp [65536,131072)
// packed [d4][e][4]; v0 @131072; c @131328; w1 @131584; w2 @131840;
// dconst {sum(bk), bq.bk, sum(bq)} (3 doubles) @132096.
//   M2[f][d] = sum_e Wq[e][f] Wk[e][d]  (u = td*(x49@M2) + v0)
//   v0[d] = sum_e bq[e] Wk[e][d];  c[d] = sum_e Wk[e][d]
//   w1[f] = sum_e bk[e] Wq[e][f];  w2[f] = sum_e Wq[e][f]
// Score paths (identical to passing rounds 1-7):
//   q-kept & s-kept : (xs_s.u + q.bk)/16   q-kept & s-mask: NEG*sum(q)/16
//   q-mask & s-kept : NEG*(xs_s.c + sum(bk))/16   both: 256e10/16
// Round-8: occupancy fix. Round-7 ran 1024 waves = 1 wave/SIMD
// (OccupancyPercent 10, VALUBusy 25 -> 75% raw stall). Same 1024 blocks,
// now 256 threads = 4 cooperating waves per block (4096 waves = 4/SIMD):
//   prologue: waves 0,2 compute xs + fp64 scalars for batch w>>1 -> LDS
//   U phase : wave w owns output group g=w for BOTH batches (M2 still
//             read exactly once per block, same coalesced b128 stream)
//   attn    : wave w -> (batch w>>1, s-half w&1); each half runs the
//             round-6-proven online-softmax loop verbatim on its
//             sub-range; partials (m,l,y) merged exactly via LDS
//   O phase : wave w owns group g=w (mirror of U with Wvp/yL)
// Per-wave serial work drops 4x; 4 waves/SIMD hide load + shuffle latency.

namespace {
constexpr int kB = 2048;
constexpr int kT = 50;
constexpr int kD = 256;
constexpr double kNeg = -100000.0;
constexpr int oM2 = 0;
constexpr int oWvp = 65536;
constexpr int oV0 = 131072;
constexpr int oC = 131328;
constexpr int oW1 = 131584;
constexpr int oW2 = 131840;
constexpr int oDbl = 132096;  // 3 doubles
}  // namespace

// ---------------- precomp: VERBATIM from rounds 5-7 (proven) --------------
__global__ __launch_bounds__(256) void precomp(
    const float* __restrict__ Wq, const float* __restrict__ bq,
    const float* __restrict__ Wk, const float* __restrict__ bk,
    const float* __restrict__ Wv, float* __restrict__ ws) {
  const int t = threadIdx.x;
  const int wave = t >> 6;
  const int lane = t & 63;
  const int blk = blockIdx.x;
  __shared__ float coefL[kD];
  __shared__ double red[3][4];

  if (blk < 256) {
    const int a = blk;
    coefL[t] = Wq[(size_t)t * kD + a];
    __syncthreads();
    const float* kcol = Wk + t;
    float pre[8];
#pragma unroll
    for (int k = 0; k < 8; ++k) pre[k] = kcol[(size_t)k * kD];
    float acc = 0.f;
    for (int j0 = 0; j0 < kD; j0 += 8) {
      float cur[8];
#pragma unroll
      for (int k = 0; k < 8; ++k) cur[k] = pre[k];
      const int nx = (j0 + 8 < kD) ? (j0 + 8) : 0;
#pragma unroll
      for (int k = 0; k < 8; ++k) pre[k] = kcol[(size_t)(nx + k) * kD];
#pragma unroll
      for (int k = 0; k < 8; ++k) acc += coefL[j0 + k] * cur[k];
    }
    ws[oM2 + (a >> 2) * 1024 + 4 * t + (a & 3)] = acc;
  } else if (blk < 258) {
    const float* W = (blk == 256) ? Wk : Wq;
    const float* coef = (blk == 256) ? bq : bk;
    coefL[t] = coef[t];
    __syncthreads();
    const float* col = W + t;
    float pre[8];
#pragma unroll
    for (int k = 0; k < 8; ++k) pre[k] = col[(size_t)k * kD];
    double a0 = 0.0, a1 = 0.0;
    for (int j0 = 0; j0 < kD; j0 += 8) {
      float cur[8];
#pragma unroll
      for (int k = 0; k < 8; ++k) cur[k] = pre[k];
      const int nx = (j0 + 8 < kD) ? (j0 + 8) : 0;
#pragma unroll
      for (int k = 0; k < 8; ++k) pre[k] = col[(size_t)(nx + k) * kD];
#pragma unroll
      for (int k = 0; k < 8; ++k) {
        const double w = (double)cur[k];
        a0 += (double)coefL[j0 + k] * w;
        a1 += w;
      }
    }
    if (blk == 256) {
      ws[oV0 + t] = (float)a0;
      ws[oC + t] = (float)a1;
    } else {
      ws[oW1 + t] = (float)a0;
      ws[oW2 + t] = (float)a1;
      double p0 = (double)bk[t];
      double p1 = (double)bq[t] * (double)bk[t];
      double p2 = (double)bq[t];
#pragma unroll
      for (int off = 32; off; off >>= 1) {
        p0 += __shfl_xor(p0, off);
        p1 += __shfl_xor(p1, off);
        p2 += __shfl_xor(p2, off);
      }
      if (lane == 0) {
        red[0][wave] = p0;
        red[1][wave] = p1;
        red[2][wave] = p2;
      }
      __syncthreads();
      if (t == 0) {
        double* dcw = (double*)(ws + oDbl);
        dcw[0] = red[0][0] + red[0][1] + red[0][2] + red[0][3];
        dcw[1] = red[1][0] + red[1][1] + red[1][2] + red[1][3];
        dcw[2] = red[2][0] + red[2][1] + red[2][2] + red[2][3];
      }
    }
  } else {
    const int d4b = (blk - 258) * 4;
    float4 in[4];
#pragma unroll
    for (int k = 0; k < 4; ++k)
      in[k] = *(const float4*)(Wv + (size_t)t * kD + 4 * (d4b + k));
    float4* Wvp = (float4*)(ws + oWvp);
#pragma unroll
    for (int k = 0; k < 4; ++k) Wvp[(size_t)(d4b + k) * kD + t] = in[k];
  }
}

// ------------- fused main: 4 cooperating waves per 2 batches --------------
__global__ __launch_bounds__(256) void fused_main(
    const float* __restrict__ x, const int* __restrict__ mask,
    const float* __restrict__ td, const float* __restrict__ bv,
    const float* __restrict__ ws, float* __restrict__ out) {
  const int tid = threadIdx.x;
  const int lane = tid & 63;
  const int w = tid >> 6;
  const int b0 = blockIdx.x * 2;
  __shared__ __align__(16) float xsL[2][kD];
  __shared__ __align__(16) float uL[2][kD];
  __shared__ __align__(16) float yL[2][kD];
  __shared__ __align__(16) float ypart[2][2][kD];
  __shared__ double mpart[2][2];
  __shared__ float lpart[2][2];
  __shared__ double dScal[2][2];  // [j][0]=Qbk, [j][1]=Sq

  const double* dc = (const double*)(ws + oDbl);
  const float4* M2v = (const float4*)(ws + oM2);
  const float4* Wvv = (const float4*)(ws + oWvp);

  // attn role for this wave, and early (latency-hidden) small loads
  const int ja = w >> 1;  // batch this wave handles in the attn phase
  const int h = w & 1;    // s-half this wave handles
  const float mtdA = (lane < kT) ? td[(size_t)(b0 + ja) * kT + lane] : 0.f;
  const int mmkA = (lane < kT) ? mask[(size_t)(b0 + ja) * kT + lane] : 0;
  const float4 c4 = ((const float4*)(ws + oC))[lane];

  // ---- prologue: waves 0,2 (h==0) compute batch ja's xs + fp64 scalars ---
  if (h == 0) {
    const int j = ja;
    const int b = b0 + j;
    const float tdl = __shfl(mtdA, kT - 1);
    const float4 a1 = ((const float4*)(ws + oW1))[lane];
    const float4 a2 = ((const float4*)(ws + oW2))[lane];
    const float4 xv =
        ((const float4*)(x + ((size_t)b * kT + kT - 1) * kD))[lane];
    double s1 = (double)xv.x * a1.x + (double)xv.y * a1.y +
                (double)xv.z * a1.z + (double)xv.w * a1.w;
    double s2 = (double)xv.x * a2.x + (double)xv.y * a2.y +
                (double)xv.z * a2.z + (double)xv.w * a2.w;
#pragma unroll
    for (int off = 32; off; off >>= 1) {
      s1 += __shfl_xor(s1, off);
      s2 += __shfl_xor(s2, off);
    }
    if (lane == 0) {
      dScal[j][0] = (double)tdl * s1 + dc[1];
      dScal[j][1] = (double)tdl * s2 + dc[2];
    }
    float4 xs;
    xs.x = xv.x * tdl; xs.y = xv.y * tdl;
    xs.z = xv.z * tdl; xs.w = xv.w * tdl;
    *(float4*)(&xsL[j][4 * lane]) = xs;
  }
  __syncthreads();

  // ---- U phase: wave w owns output group g=w for both batches ----
  {
    const int col = 64 * w + lane;
    float4 A = M2v[col];
    float4 B = M2v[256 + col];
    float acc0 = 0.f, acc1 = 0.f;
    for (int k4 = 0; k4 < 64; k4 += 2) {
      const float4 c0 = A, c1 = B;
      const int n0 = (k4 + 2 < 64) ? k4 + 2 : 0;
      const int n1 = (k4 + 3 < 64) ? k4 + 3 : 1;
      A = M2v[(size_t)n0 * 256 + col];
      B = M2v[(size_t)n1 * 256 + col];
      const float4 x00 = *(const float4*)(&xsL[0][4 * k4]);
      const float4 x01 = *(const float4*)(&xsL[0][4 * (k4 + 1)]);
      const float4 x10 = *(const float4*)(&xsL[1][4 * k4]);
      const float4 x11 = *(const float4*)(&xsL[1][4 * (k4 + 1)]);
      acc0 += x00.x * c0.x + x00.y * c0.y + x00.z * c0.z + x00.w * c0.w +
              x01.x * c1.x + x01.y * c1.y + x01.z * c1.z + x01.w * c1.w;
      acc1 += x10.x * c0.x + x10.y * c0.y + x10.z * c0.z + x10.w * c0.w +
              x11.x * c1.x + x11.y * c1.y + x11.z * c1.z + x11.w * c1.w;
    }
    const float v0g = ws[oV0 + col];
    uL[0][col] = acc0 + v0g;
    uL[1][col] = acc1 + v0g;
  }
  __syncthreads();

  // ---- attention: wave w -> (batch ja, s-half h); round-6 body verbatim
  //      on the sub-range; partials merged exactly after the barrier ----
  {
    const int j = ja;
    const int b = b0 + j;
    const float mtd = mtdA;
    const int mmk = mmkA;
    const int mqg = __shfl(mmk, kT - 1);
    const float4 u4 = *(const float4*)(&uL[j][4 * lane]);
    const float4 v4 = mqg ? u4 : c4;
    const double Qb = dScal[j][0];
    const double Cm = kNeg * dScal[j][1] * 0.0625;
    const double sbkd = dc[0];
    const double Cbb = 256.0 * 1.0e10 * 0.0625;
    // h==0: s in [0,24) rows 0..23 (6 iters; this wave also merges later)
    // h==1: s in [24,52) rows 24..49 + killed 50,51 (7 iters)
    const int sbeg = h ? 24 : 0;
    const int slim = h ? 52 : 24;

    const float4* xrow = (const float4*)(x + (size_t)b * kT * kD);
    double m = -1.0e300;
    float l = 0.f;
    float4 y = {0.f, 0.f, 0.f, 0.f};

    float4 n0 = xrow[(size_t)(sbeg + 0) * 64 + lane];
    float4 n1 = xrow[(size_t)(sbeg + 1) * 64 + lane];
    float4 n2 = xrow[(size_t)(sbeg + 2) * 64 + lane];
    float4 n3 = xrow[(size_t)(sbeg + 3) * 64 + lane];
    for (int s = sbeg; s < slim; s += 4) {
      const float4 r0 = n0, r1 = n1, r2 = n2, r3 = n3;
      {
        const int p0 = (s + 4 < kT) ? s + 4 : kT - 1;
        const int p1 = (s + 5 < kT) ? s + 5 : kT - 1;
        const int p2 = (s + 6 < kT) ? s + 6 : kT - 1;
        const int p3 = (s + 7 < kT) ? s + 7 : kT - 1;
        n0 = xrow[(size_t)p0 * 64 + lane];
        n1 = xrow[(size_t)p1 * 64 + lane];
        n2 = xrow[(size_t)p2 * 64 + lane];
        n3 = xrow[(size_t)p3 * 64 + lane];
      }
      const int s1i = s + 1, s2i = s + 2, s3i = s + 3;
      const int cc0 = s;
      const int cc1 = (s1i < kT) ? s1i : kT - 1;
      const int cc2 = (s2i < kT) ? s2i : kT - 1;
      const int cc3 = (s3i < kT) ? s3i : kT - 1;
      const float tv0 = __shfl(mtd, cc0);
      const float tv1 = __shfl(mtd, cc1);
      const float tv2 = __shfl(mtd, cc2);
      const float tv3 = __shfl(mtd, cc3);
      float4 a0, aa1, a2v, a3;
      a0.x = r0.x * tv0; a0.y = r0.y * tv0; a0.z = r0.z * tv0; a0.w = r0.w * tv0;
      aa1.x = r1.x * tv1; aa1.y = r1.y * tv1; aa1.z = r1.z * tv1; aa1.w = r1.w * tv1;
      a2v.x = r2.x * tv2; a2v.y = r2.y * tv2; a2v.z = r2.z * tv2; a2v.w = r2.w * tv2;
      a3.x = r3.x * tv3; a3.y = r3.y * tv3; a3.z = r3.z * tv3; a3.w = r3.w * tv3;
      float p0 = a0.x * v4.x + a0.y * v4.y + a0.z * v4.z + a0.w * v4.w;
      float p1 = aa1.x * v4.x + aa1.y * v4.y + aa1.z * v4.z + aa1.w * v4.w;
      float p2 = a2v.x * v4.x + a2v.y * v4.y + a2v.z * v4.z + a2v.w * v4.w;
      float p3 = a3.x * v4.x + a3.y * v4.y + a3.z * v4.z + a3.w * v4.w;
#pragma unroll
      for (int off = 32; off; off >>= 1) {
        p0 += __shfl_xor(p0, off);
        p1 += __shfl_xor(p1, off);
        p2 += __shfl_xor(p2, off);
        p3 += __shfl_xor(p3, off);
      }
      const int ms0 = __shfl(mmk, cc0);
      const int ms1 = __shfl(mmk, cc1);
      const int ms2 = __shfl(mmk, cc2);
      const int ms3 = __shfl(mmk, cc3);
      double sc0, sc1, sc2, sc3;
      if (mqg) {
        sc0 = ms0 ? ((double)p0 + Qb) * 0.0625 : Cm;
        sc1 = ms1 ? ((double)p1 + Qb) * 0.0625 : Cm;
        sc2 = ms2 ? ((double)p2 + Qb) * 0.0625 : Cm;
        sc3 = ms3 ? ((double)p3 + Qb) * 0.0625 : Cm;
      } else {
        sc0 = ms0 ? kNeg * ((double)p0 + sbkd) * 0.0625 : Cbb;
        sc1 = ms1 ? kNeg * ((double)p1 + sbkd) * 0.0625 : Cbb;
        sc2 = ms2 ? kNeg * ((double)p2 + sbkd) * 0.0625 : Cbb;
        sc3 = ms3 ? kNeg * ((double)p3 + sbkd) * 0.0625 : Cbb;
      }
      if (s1i >= kT) sc1 = -1.0e300;
      if (s2i >= kT) sc2 = -1.0e300;
      if (s3i >= kT) sc3 = -1.0e300;
      double mnew = m;
      if (sc0 > mnew) mnew = sc0;
      if (sc1 > mnew) mnew = sc1;
      if (sc2 > mnew) mnew = sc2;
      if (sc3 > mnew) mnew = sc3;
      const float al = expf((float)(m - mnew));
      const float e0 = expf((float)(sc0 - mnew));
      const float e1 = expf((float)(sc1 - mnew));
      const float e2 = expf((float)(sc2 - mnew));
      const float e3 = expf((float)(sc3 - mnew));
      m = mnew;
      l = l * al + e0 + e1 + e2 + e3;
      y.x = y.x * al + e0 * a0.x + e1 * aa1.x + e2 * a2v.x + e3 * a3.x;
      y.y = y.y * al + e0 * a0.y + e1 * aa1.y + e2 * a2v.y + e3 * a3.y;
      y.z = y.z * al + e0 * a0.z + e1 * aa1.z + e2 * a2v.z + e3 * a3.z;
      y.w = y.w * al + e0 * a0.w + e1 * aa1.w + e2 * a2v.w + e3 * a3.w;
    }
    if (lane == 0) {
      mpart[j][h] = m;
      lpart[j][h] = l;
    }
    *(float4*)(&ypart[j][h][4 * lane]) = y;
  }
  __syncthreads();

  // ---- merge the two online-softmax partials (exact) + normalize ----
  if (h == 0) {
    const int j = ja;
    const double m0 = mpart[j][0], m1 = mpart[j][1];
    const double M = (m0 > m1) ? m0 : m1;
    const float e0 = expf((float)(m0 - M));
    const float e1 = expf((float)(m1 - M));
    const float l = lpart[j][0] * e0 + lpart[j][1] * e1;
    const float inv = 1.0f / l;
    const float4 y0 = *(const float4*)(&ypart[j][0][4 * lane]);
    const float4 y1 = *(const float4*)(&ypart[j][1][4 * lane]);
    float4 yv;
    yv.x = (y0.x * e0 + y1.x * e1) * inv;
    yv.y = (y0.y * e0 + y1.y * e1) * inv;
    yv.z = (y0.z * e0 + y1.z * e1) * inv;
    yv.w = (y0.w * e0 + y1.w * e1) * inv;
    *(float4*)(&yL[j][4 * lane]) = yv;
  }
  __syncthreads();

  // ---- O phase: wave w owns group g=w; mirror of U with Wvp / yL ----
  {
    const int col = 64 * w + lane;
    float4 A = Wvv[col];
    float4 B = Wvv[256 + col];
    float acc0 = 0.f, acc1 = 0.f;
    for (int k4 = 0; k4 < 64; k4 += 2) {
      const float4 c0 = A, c1 = B;
      const int n0 = (k4 + 2 < 64) ? k4 + 2 : 0;
      const int n1 = (k4 + 3 < 64) ? k4 + 3 : 1;
      A = Wvv[(size_t)n0 * 256 + col];
      B = Wvv[(size_t)n1 * 256 + col];
      const float4 y00 = *(const float4*)(&yL[0][4 * k4]);
      const float4 y01 = *(const float4*)(&yL[0][4 * (k4 + 1)]);
      const float4 y10 = *(const float4*)(&yL[1][4 * k4]);
      const float4 y11 = *(const float4*)(&yL[1][4 * (k4 + 1)]);
      acc0 += y00.x * c0.x + y00.y * c0.y + y00.z * c0.z + y00.w * c0.w +
              y01.x * c1.x + y01.y * c1.y + y01.z * c1.z + y01.w * c1.w;
      acc1 += y10.x * c0.x + y10.y * c0.y + y10.z * c0.z + y10.w * c0.w +
              y11.x * c1.x + y11.y * c1.y + y11.z * c1.z + y11.w * c1.w;
    }
    const float bvg = bv[col];
    out[(size_t)(b0 + 0) * kD + col] = acc0 + bvg;
    out[(size_t)(b0 + 1) * kD + col] = acc1 + bvg;
  }
}

extern "C" void kernel_launch(void* const* d_in, const int* in_sizes, int n_in,
                              void* d_out, int out_size, void* d_ws,
                              size_t ws_size, hipStream_t stream) {
  const float* x = (const float*)d_in[0];
  const int* mask = (const int*)d_in[1];
  const float* td = (const float*)d_in[2];
  const float* Wq = (const float*)d_in[3];
  const float* bq = (const float*)d_in[4];
  const float* Wk = (const float*)d_in[5];
  const float* bk = (const float*)d_in[6];
  const float* Wv = (const float*)d_in[7];
  const float* bv = (const float*)d_in[8];
  float* ws = (float*)d_ws;  // ~530 KB used
  float* out = (float*)d_out;
  (void)in_sizes; (void)n_in; (void)out_size; (void)ws_size;

  hipLaunchKernelGGL(precomp, dim3(274), dim3(256), 0, stream, Wq, bq, Wk, bk,
                     Wv, ws);
  hipLaunchKernelGGL(fused_main, dim3(kB / 2), dim3(256), 0, stream, x, mask,
                     td, bv, (const float*)ws, out);
}